// Round 1
// baseline (362.940 us; speedup 1.0000x reference)
//
#include <hip/hip_runtime.h>
#include <cstdint>
#include <cstddef>

// Shapes (fixed by the reference)
// B=1024, N=2, HIST=64, D=256, E=128, NH=8, HD=32, s=128; queries kept: s=63 (q=0), s=127 (q=1)

typedef short bf16x8 __attribute__((ext_vector_type(8)));
typedef float f32x4 __attribute__((ext_vector_type(4)));

#define MFMA16(A, B, C) __builtin_amdgcn_mfma_f32_16x16x32_bf16((A), (B), (C), 0, 0, 0)

static __device__ __forceinline__ uint16_t f2bf(float f) {
    uint32_t u = __builtin_bit_cast(uint32_t, f);
    u += 0x7FFFu + ((u >> 16) & 1u);
    return (uint16_t)(u >> 16);
}
static __device__ __forceinline__ uint32_t pack2(float a, float b) {
    return (uint32_t)f2bf(a) | ((uint32_t)f2bf(b) << 16);
}

// ---------------------------------------------------------------------------
// K0: transpose Wq/Wv/Wo (fp32 [k][n]) -> bf16 [n][264] (k-contiguous rows)
// ---------------------------------------------------------------------------
__global__ __launch_bounds__(256) void k_wt(
    const float* __restrict__ Wq, const float* __restrict__ Wv, const float* __restrict__ Wo,
    uint16_t* __restrict__ WqT, uint16_t* __restrict__ WvT, uint16_t* __restrict__ WoT)
{
    const float* W = (blockIdx.z == 0) ? Wq : ((blockIdx.z == 1) ? Wv : Wo);
    uint16_t* O = (blockIdx.z == 0) ? WqT : ((blockIdx.z == 1) ? WvT : WoT);
    __shared__ float tile[64][65];
    const int t = threadIdx.x;
    const int tr = blockIdx.x, tc = blockIdx.y;
    #pragma unroll
    for (int i = 0; i < 16; i++) {
        int flat = i * 256 + t;
        int lr = flat >> 6, lc = flat & 63;
        tile[lr][lc] = W[(size_t)(tr * 64 + lr) * 256 + tc * 64 + lc];
    }
    __syncthreads();
    #pragma unroll
    for (int i = 0; i < 16; i++) {
        int flat = i * 256 + t;
        int orow = flat >> 6, oc = flat & 63;
        O[(size_t)(tc * 64 + orow) * 264 + tr * 64 + oc] = f2bf(tile[oc][orow]);
    }
}

// ---------------------------------------------------------------------------
// K1: heterogeneous prep.
//  blocks [0,256): edge modulations -> sp=(1+tanh)*sig gate, tp=shift*gate, ebhs
//  blocks [256,272): Q = x_q @ Wq + bq (MFMA), then U[kd][(q,h)] = sum_j Q*Wk (MFMA)
// ---------------------------------------------------------------------------
__global__ __launch_bounds__(256, 2) void k_prep(
    const float* __restrict__ edge,
    const float* __restrict__ Wgate, const float* __restrict__ bgate,
    const float* __restrict__ Wscale, const float* __restrict__ bscale,
    const float* __restrict__ Wshift, const float* __restrict__ bshift,
    const float* __restrict__ Wbias, const float* __restrict__ bbias,
    const float* __restrict__ Whead, const float* __restrict__ bhead,
    const float* __restrict__ node, const uint16_t* __restrict__ WqT,
    const float* __restrict__ Wk, const float* __restrict__ bq,
    float* __restrict__ sp, float* __restrict__ tp,
    float* __restrict__ ebhs, uint16_t* __restrict__ U)
{
    __shared__ char smem[65536];
    const int t = threadIdx.x;
    if (blockIdx.x < 256) {
        // ---- role A: edge modulations, 4 batches per block ----
        float* eL = (float*)smem; // [4][128]
        const int b0 = blockIdx.x * 4;
        for (int idx = t; idx < 512; idx += 256) {
            int bi = idx >> 7, e = idx & 127;
            eL[bi * 128 + e] = edge[(size_t)(b0 + bi) * 128 + e];
        }
        __syncthreads();
        float ag[4] = {0, 0, 0, 0}, asr[4] = {0, 0, 0, 0}, ah[4] = {0, 0, 0, 0};
        for (int e = 0; e < 128; e++) {
            float wg = Wgate[e * 256 + t];
            float wsc = Wscale[e * 256 + t];
            float wsh = Wshift[e * 256 + t];
            #pragma unroll
            for (int bi = 0; bi < 4; bi++) {
                float xv = eL[bi * 128 + e];
                ag[bi] = fmaf(xv, wg, ag[bi]);
                asr[bi] = fmaf(xv, wsc, asr[bi]);
                ah[bi] = fmaf(xv, wsh, ah[bi]);
            }
        }
        float bg = bgate[t], bs = bscale[t], bsh = bshift[t];
        #pragma unroll
        for (int bi = 0; bi < 4; bi++) {
            float g = 1.0f / (1.0f + __expf(-(ag[bi] + bg)));
            float sc = tanhf(asr[bi] + bs);
            float sh = ah[bi] + bsh;
            sp[(size_t)(b0 + bi) * 256 + t] = (1.0f + sc) * g;
            tp[(size_t)(b0 + bi) * 256 + t] = sh * g;
        }
        if (t < 64) {
            int bi = t >> 4, o = t & 15, h = o & 7;
            const float* W = (o < 8) ? Wbias : Whead;
            float a = 0.0f;
            for (int e = 0; e < 128; e++) a = fmaf(eL[bi * 128 + e], W[e * 8 + h], a);
            float val = (o < 8) ? (a + bbias[h]) : tanhf(a + bhead[h]);
            ebhs[(size_t)(b0 + bi) * 16 + o] = val;
        }
    } else {
        // ---- role B: Q then U, 64 batches (128 q-rows) per block ----
        uint16_t* xq = (uint16_t*)smem; // XOR-swizzled [128][256] bf16, 64 KB
        const int rb = blockIdx.x - 256;
        const int lane = t & 63, w = t >> 6, c = lane & 15, quad = lane >> 4;
        #pragma unroll
        for (int i = 0; i < 32; i++) {
            int flat4 = i * 256 + t;
            int row = flat4 >> 6, c4 = flat4 & 63;
            int bb = rb * 64 + (row >> 1);
            int s = (row & 1) ? 127 : 63;
            const float4 v = *(const float4*)(node + ((size_t)(bb * 128 + s)) * 256 + c4 * 4);
            int phys = (c4 >> 1) ^ (row & 31); // 16B-chunk xor swizzle
            uint2 pv; pv.x = pack2(v.x, v.y); pv.y = pack2(v.z, v.w);
            *(uint2*)&xq[row * 256 + phys * 8 + (c4 & 1) * 4] = pv;
        }
        __syncthreads();
        // GEMM1: Q (128x256) = xq(128x256) @ Wq(256x256); wave w -> M-tiles 2w,2w+1
        f32x4 zero = {0, 0, 0, 0};
        f32x4 acc[2][16];
        #pragma unroll
        for (int mt = 0; mt < 2; mt++)
            #pragma unroll
            for (int nt = 0; nt < 16; nt++) acc[mt][nt] = zero;
        #pragma unroll
        for (int nt = 0; nt < 16; nt++) {
            #pragma unroll
            for (int kk = 0; kk < 8; kk++) {
                bf16x8 bfr = *(const bf16x8*)&WqT[(size_t)(nt * 16 + c) * 264 + kk * 32 + quad * 8];
                #pragma unroll
                for (int mt = 0; mt < 2; mt++) {
                    int row = (w * 2 + mt) * 16 + c;
                    int phys = (kk * 4 + quad) ^ (row & 31);
                    bf16x8 afr = *(const bf16x8*)&xq[row * 256 + phys * 8];
                    acc[mt][nt] = MFMA16(afr, bfr, acc[mt][nt]);
                }
            }
        }
        // epilogue: Q overwrites xq (each wave overwrites only its own A-rows)
        #pragma unroll
        for (int nt = 0; nt < 16; nt++) {
            float bqv = bq[nt * 16 + c];
            #pragma unroll
            for (int mt = 0; mt < 2; mt++) {
                #pragma unroll
                for (int r = 0; r < 4; r++) {
                    int row = (w * 2 + mt) * 16 + quad * 4 + r;
                    int col2 = nt * 16 + c;
                    int phys = (col2 >> 3) ^ (row & 31);
                    xq[row * 256 + phys * 8 + (col2 & 7)] = f2bf(acc[mt][nt][r] + bqv);
                }
            }
        }
        __syncthreads();
        // GEMM2: U^T[kd][(b,q)] per head. A = Wk rows (global fp32), B = Q (LDS)
        for (int hh = 0; hh < 8; hh++) {
            bf16x8 bfr[2];
            #pragma unroll
            for (int j = 0; j < 2; j++) {
                int nrow = (w * 2 + j) * 16 + c;
                int phys = (hh * 4 + quad) ^ (nrow & 31);
                bfr[j] = *(const bf16x8*)&xq[nrow * 256 + phys * 8];
            }
            for (int mt = 0; mt < 16; mt++) {
                const float* ap = Wk + (size_t)(mt * 16 + c) * 256 + hh * 32 + quad * 8;
                float4 a0 = *(const float4*)ap;
                float4 a1 = *(const float4*)(ap + 4);
                union { bf16x8 v; uint16_t s[8]; } af;
                af.s[0] = f2bf(a0.x); af.s[1] = f2bf(a0.y); af.s[2] = f2bf(a0.z); af.s[3] = f2bf(a0.w);
                af.s[4] = f2bf(a1.x); af.s[5] = f2bf(a1.y); af.s[6] = f2bf(a1.z); af.s[7] = f2bf(a1.w);
                #pragma unroll
                for (int j = 0; j < 2; j++) {
                    f32x4 d = zero;
                    d = MFMA16(af.v, bfr[j], d);
                    int R = (w * 2 + j) * 16 + c;      // (b,q) index
                    int bb = rb * 64 + (R >> 1);
                    int qh = (R & 1) * 8 + hh;
                    int kd0 = mt * 16 + quad * 4;
                    uint2 pk; pk.x = pack2(d[0], d[1]); pk.y = pack2(d[2], d[3]);
                    *(uint2*)&U[((size_t)(bb * 16 + qh)) * 256 + kd0] = pk;
                }
            }
        }
    }
}

// ---------------------------------------------------------------------------
// K2 (hot): per batch: stream x once; S = x@U; online softmax (2 chunks of 64
// keys); Y = p@x accumulated in regs with alpha-rescale; write Y bf16.
// LDS ~45 KB -> 3 blocks/CU.
// ---------------------------------------------------------------------------
__global__ __launch_bounds__(256, 2) void k_main(
    const float* __restrict__ node,
    const uint16_t* __restrict__ U,
    const float* __restrict__ ebhs,
    uint16_t* __restrict__ Y)
{
    __shared__ uint16_t xc[64 * 264];   // x chunk bf16 (padded stride)
    __shared__ uint16_t uL[16 * 264];   // U^T rows [(q,h)][kd]
    __shared__ uint16_t pL[16 * 72];    // unnormalized p chunk [(q,h)][64]
    __shared__ float wred[2][16][4];
    __shared__ float stM[16], stL[16], stA[16];
    __shared__ float ebhsL[16];
    const int b = blockIdx.x;
    const int t = threadIdx.x, lane = t & 63, w = t >> 6, c = lane & 15, quad = lane >> 4;
    #pragma unroll
    for (int i = 0; i < 2; i++) {
        int flat = i * 256 + t;
        int row = flat >> 5, c16 = flat & 31;
        uint4 v = *(const uint4*)&U[((size_t)b * 16 + row) * 256 + c16 * 8];
        *(uint4*)&uL[row * 264 + c16 * 8] = v;
    }
    if (t < 16) { ebhsL[t] = ebhs[(size_t)b * 16 + t]; stM[t] = -1e30f; stL[t] = 0.0f; }
    __syncthreads();
    const int q = c >> 3, h = c & 7;
    const float scaleF = 0.17677669529663687f * (1.0f + ebhsL[8 + h]); // 1/sqrt(32)*(1+hs)
    const float ebv = ebhsL[h];
    f32x4 zero = {0, 0, 0, 0};
    f32x4 yacc[4];
    #pragma unroll
    for (int tt = 0; tt < 4; tt++) yacc[tt] = zero;

    for (int ch = 0; ch < 2; ch++) {
        // stage x chunk (64 rows x 256 fp32 -> bf16)
        #pragma unroll
        for (int i = 0; i < 16; i++) {
            int flat4 = i * 256 + t;
            int row = flat4 >> 6, c4 = flat4 & 63;
            const float4 v = *(const float4*)(node + ((size_t)b * 128 + ch * 64 + row) * 256 + c4 * 4);
            uint2 pv; pv.x = pack2(v.x, v.y); pv.y = pack2(v.z, v.w);
            *(uint2*)&xc[row * 264 + c4 * 4] = pv;
        }
        __syncthreads();
        // S chunk: wave w -> key rows [16w,16w+16)
        f32x4 sacc = zero;
        #pragma unroll
        for (int kk = 0; kk < 8; kk++) {
            bf16x8 afr = *(const bf16x8*)&xc[(w * 16 + c) * 264 + kk * 32 + quad * 8];
            bf16x8 bfr = *(const bf16x8*)&uL[c * 264 + kk * 32 + quad * 8];
            sacc = MFMA16(afr, bfr, sacc);
        }
        float v0[4];
        #pragma unroll
        for (int r = 0; r < 4; r++) {
            int krow = ch * 64 + w * 16 + quad * 4 + r;
            float x = sacc[r] * scaleF;
            if ((q == 0 && krow == 127) || (q == 1 && krow == 63)) x += ebv;
            v0[r] = x;
        }
        // online softmax bookkeeping
        float lmax = fmaxf(fmaxf(v0[0], v0[1]), fmaxf(v0[2], v0[3]));
        lmax = fmaxf(lmax, __shfl_xor(lmax, 16, 64));
        lmax = fmaxf(lmax, __shfl_xor(lmax, 32, 64));
        if (lane < 16) wred[0][c][w] = lmax;
        __syncthreads();
        float cmax = fmaxf(fmaxf(wred[0][c][0], wred[0][c][1]), fmaxf(wred[0][c][2], wred[0][c][3]));
        float mold = stM[c];
        float mnew = fmaxf(mold, cmax);
        float alpha = __expf(mold - mnew);
        float p0[4]; float lsum = 0.0f;
        #pragma unroll
        for (int r = 0; r < 4; r++) { p0[r] = __expf(v0[r] - mnew); lsum += p0[r]; }
        lsum += __shfl_xor(lsum, 16, 64);
        lsum += __shfl_xor(lsum, 32, 64);
        if (lane < 16) wred[1][c][w] = lsum;
        __syncthreads();
        if (w == 0 && lane < 16) {
            float csum = wred[1][c][0] + wred[1][c][1] + wred[1][c][2] + wred[1][c][3];
            stL[c] = stL[c] * alpha + csum;
            stM[c] = mnew;
            stA[c] = alpha;
        }
        {
            uint2 pk; pk.x = pack2(p0[0], p0[1]); pk.y = pack2(p0[2], p0[3]);
            *(uint2*)&pL[c * 72 + w * 16 + quad * 4] = pk;
        }
        __syncthreads();
        // Y chunk: rescale acc by alpha(row qh), then p @ x_chunk
        float av[4];
        #pragma unroll
        for (int r = 0; r < 4; r++) av[r] = stA[quad * 4 + r];
        #pragma unroll
        for (int tt = 0; tt < 4; tt++)
            #pragma unroll
            for (int r = 0; r < 4; r++) yacc[tt][r] *= av[r];
        #pragma unroll
        for (int kk = 0; kk < 2; kk++) {
            bf16x8 afr = *(const bf16x8*)&pL[c * 72 + kk * 32 + quad * 8];
            int kbase = kk * 32 + quad * 8;
            #pragma unroll
            for (int tt = 0; tt < 4; tt++) {
                int n = w * 64 + tt * 16 + c;
                union { bf16x8 v; uint32_t u[4]; } bb;
                #pragma unroll
                for (int jj = 0; jj < 4; jj++) {
                    uint32_t lo = xc[(kbase + 2 * jj) * 264 + n];
                    uint32_t hi = xc[(kbase + 2 * jj + 1) * 264 + n];
                    bb.u[jj] = lo | (hi << 16);
                }
                yacc[tt] = MFMA16(afr, bb.v, yacc[tt]);
            }
        }
        __syncthreads();
    }
    float invl[4];
    #pragma unroll
    for (int r = 0; r < 4; r++) invl[r] = 1.0f / stL[quad * 4 + r];
    #pragma unroll
    for (int tt = 0; tt < 4; tt++) {
        int n = w * 64 + tt * 16 + c;
        #pragma unroll
        for (int r = 0; r < 4; r++) {
            int qh = quad * 4 + r;
            Y[((size_t)b * 16 + qh) * 256 + n] = f2bf(yacc[tt][r] * invl[r]);
        }
    }
}

// ---------------------------------------------------------------------------
// K3: out = ((Y_h @ Wv_h + bv) * s' + t') @ Wo + bo.  32 (b,q)-rows per block.
// ---------------------------------------------------------------------------
__global__ __launch_bounds__(256, 2) void k_out(
    const uint16_t* __restrict__ Y,
    const uint16_t* __restrict__ WvT, const uint16_t* __restrict__ WoT,
    const float* __restrict__ bv, const float* __restrict__ bo,
    const float* __restrict__ sp, const float* __restrict__ tp,
    float* __restrict__ out)
{
    __shared__ uint16_t yh[32 * 264];
    __shared__ uint16_t zm[32 * 264];
    const int t = threadIdx.x, lane = t & 63, w = t >> 6, c = lane & 15, quad = lane >> 4;
    const int r0 = blockIdx.x * 32;
    f32x4 zero = {0, 0, 0, 0};
    for (int h = 0; h < 8; h++) {
        __syncthreads();
        #pragma unroll
        for (int i = 0; i < 4; i++) {
            int flat = i * 256 + t;
            int row = flat >> 5, c16 = flat & 31;
            int R = r0 + row; int b = R >> 1, q = R & 1;
            uint4 v = *(const uint4*)&Y[((size_t)(b * 16) + q * 8 + h) * 256 + c16 * 8];
            *(uint4*)&yh[row * 264 + c16 * 8] = v;
        }
        __syncthreads();
        int mt = w >> 1, nt = w & 1;
        f32x4 zacc = zero;
        #pragma unroll
        for (int kk = 0; kk < 8; kk++) {
            bf16x8 afr = *(const bf16x8*)&yh[(mt * 16 + c) * 264 + kk * 32 + quad * 8];
            bf16x8 bfr = *(const bf16x8*)&WvT[(size_t)(h * 32 + nt * 16 + c) * 264 + kk * 32 + quad * 8];
            zacc = MFMA16(afr, bfr, zacc);
        }
        int col = h * 32 + nt * 16 + c;
        float bvv = bv[col];
        #pragma unroll
        for (int r = 0; r < 4; r++) {
            int row = mt * 16 + quad * 4 + r;
            int R = r0 + row; int b = R >> 1;
            float z = zacc[r] + bvv;
            float spv = sp[(size_t)b * 256 + col];
            float tpv = tp[(size_t)b * 256 + col];
            zm[row * 264 + col] = f2bf(z * spv + tpv);
        }
    }
    __syncthreads();
    // final: (32x256) @ Wo(256x256) + bo -> fp32 out
    for (int i = 0; i < 4; i++) {
        int nt = w * 4 + i;
        int n = nt * 16 + c;
        for (int mt2 = 0; mt2 < 2; mt2++) {
            f32x4 fa = zero;
            #pragma unroll
            for (int kk = 0; kk < 8; kk++) {
                bf16x8 afr = *(const bf16x8*)&zm[(mt2 * 16 + c) * 264 + kk * 32 + quad * 8];
                bf16x8 bfr = *(const bf16x8*)&WoT[(size_t)n * 264 + kk * 32 + quad * 8];
                fa = MFMA16(afr, bfr, fa);
            }
            float bov = bo[n];
            #pragma unroll
            for (int r = 0; r < 4; r++) {
                out[(size_t)(r0 + mt2 * 16 + quad * 4 + r) * 256 + n] = fa[r] + bov;
            }
        }
    }
}

// ---------------------------------------------------------------------------
extern "C" void kernel_launch(void* const* d_in, const int* in_sizes, int n_in,
                              void* d_out, int out_size, void* d_ws, size_t ws_size,
                              hipStream_t stream) {
    const float* node   = (const float*)d_in[0];
    const float* edge   = (const float*)d_in[1];
    const float* Wq     = (const float*)d_in[2];
    const float* bq     = (const float*)d_in[3];
    const float* Wk     = (const float*)d_in[4];
    // d_in[5] = bk : provably unused (softmax-shift invariant)
    const float* Wv     = (const float*)d_in[6];
    const float* bv     = (const float*)d_in[7];
    const float* Wo     = (const float*)d_in[8];
    const float* bo     = (const float*)d_in[9];
    const float* Wbias  = (const float*)d_in[10];
    const float* bbias  = (const float*)d_in[11];
    const float* Wgate  = (const float*)d_in[12];
    const float* bgate  = (const float*)d_in[13];
    const float* Wscale = (const float*)d_in[14];
    const float* bscale = (const float*)d_in[15];
    const float* Wshift = (const float*)d_in[16];
    const float* bshift = (const float*)d_in[17];
    const float* Whead  = (const float*)d_in[18];
    const float* bhead  = (const float*)d_in[19];

    char* ws = (char*)d_ws;
    uint16_t* WqT  = (uint16_t*)(ws + 0);         // 256*264*2 = 135168
    uint16_t* WvT  = (uint16_t*)(ws + 135168);
    uint16_t* WoT  = (uint16_t*)(ws + 270336);
    float*    spw  = (float*)(ws + 405504);       // 1 MB
    float*    tpw  = (float*)(ws + 1454080);      // 1 MB
    float*    ebhs = (float*)(ws + 2502656);      // 64 KB
    uint16_t* Uw   = (uint16_t*)(ws + 2568192);   // 8 MB
    uint16_t* Yw   = (uint16_t*)(ws + 10956800);  // 8 MB  (total ~19.3 MB)

    k_wt<<<dim3(4, 4, 3), 256, 0, stream>>>(Wq, Wv, Wo, WqT, WvT, WoT);
    k_prep<<<272, 256, 0, stream>>>(edge, Wgate, bgate, Wscale, bscale, Wshift, bshift,
                                    Wbias, bbias, Whead, bhead,
                                    node, WqT, Wk, bq, spw, tpw, ebhs, Uw);
    k_main<<<1024, 256, 0, stream>>>(node, Uw, ebhs, Yw);
    k_out<<<64, 256, 0, stream>>>(Yw, WvT, WoT, bv, bo, spw, tpw, (float*)d_out);
}

// Round 2
// 289.915 us; speedup vs baseline: 1.2519x; 1.2519x over previous
//
#include <hip/hip_runtime.h>
#include <cstdint>
#include <cstddef>

// Shapes (fixed): B=1024, N=2, HIST=64, D=256, E=128, NH=8, HD=32, s=128
// queries kept: s=63 (q=0), s=127 (q=1)

typedef short bf16x8 __attribute__((ext_vector_type(8)));
typedef float f32x4 __attribute__((ext_vector_type(4)));

#define MFMA16(A, B, C) __builtin_amdgcn_mfma_f32_16x16x32_bf16((A), (B), (C), 0, 0, 0)

static __device__ __forceinline__ uint16_t f2bf(float f) {
    uint32_t u = __builtin_bit_cast(uint32_t, f);
    u += 0x7FFFu + ((u >> 16) & 1u);
    return (uint16_t)(u >> 16);
}
static __device__ __forceinline__ uint32_t pack2(float a, float b) {
    return (uint32_t)f2bf(a) | ((uint32_t)f2bf(b) << 16);
}

// ---------------------------------------------------------------------------
// K0: z<3: transpose Wq/Wv/Wo (fp32 [k][n]) -> bf16 [n][264]
//     z==3: straight-convert Wk (fp32 [j][d]) -> bf16 [j][264]
// ---------------------------------------------------------------------------
__global__ __launch_bounds__(256) void k_wt(
    const float* __restrict__ Wq, const float* __restrict__ Wv,
    const float* __restrict__ Wo, const float* __restrict__ Wk,
    uint16_t* __restrict__ WqT, uint16_t* __restrict__ WvT,
    uint16_t* __restrict__ WoT, uint16_t* __restrict__ WkB)
{
    const int t = threadIdx.x;
    const int tr = blockIdx.x, tc = blockIdx.y, z = blockIdx.z;
    if (z == 3) {
        #pragma unroll
        for (int i = 0; i < 16; i++) {
            int flat = i * 256 + t;
            int lr = flat >> 6, lc = flat & 63;
            WkB[(size_t)(tr * 64 + lr) * 264 + tc * 64 + lc] =
                f2bf(Wk[(size_t)(tr * 64 + lr) * 256 + tc * 64 + lc]);
        }
        return;
    }
    const float* W = (z == 0) ? Wq : ((z == 1) ? Wv : Wo);
    uint16_t* O = (z == 0) ? WqT : ((z == 1) ? WvT : WoT);
    __shared__ float tile[64][65];
    #pragma unroll
    for (int i = 0; i < 16; i++) {
        int flat = i * 256 + t;
        int lr = flat >> 6, lc = flat & 63;
        tile[lr][lc] = W[(size_t)(tr * 64 + lr) * 256 + tc * 64 + lc];
    }
    __syncthreads();
    #pragma unroll
    for (int i = 0; i < 16; i++) {
        int flat = i * 256 + t;
        int orow = flat >> 6, oc = flat & 63;
        O[(size_t)(tc * 64 + orow) * 264 + tr * 64 + oc] = f2bf(tile[oc][orow]);
    }
}

// ---------------------------------------------------------------------------
// K1: edge modulations. 256 blocks x 4 batches.
// sp=(1+tanh(scale))*sigmoid(gate), tp=shift*gate, ebhs=[edge_bias(8),head_scale(8)]
// ---------------------------------------------------------------------------
__global__ __launch_bounds__(256) void k_edge(
    const float* __restrict__ edge,
    const float* __restrict__ Wgate, const float* __restrict__ bgate,
    const float* __restrict__ Wscale, const float* __restrict__ bscale,
    const float* __restrict__ Wshift, const float* __restrict__ bshift,
    const float* __restrict__ Wbias, const float* __restrict__ bbias,
    const float* __restrict__ Whead, const float* __restrict__ bhead,
    float* __restrict__ sp, float* __restrict__ tp, float* __restrict__ ebhs)
{
    __shared__ float eL[512];
    const int t = threadIdx.x;
    const int b0 = blockIdx.x * 4;
    for (int idx = t; idx < 512; idx += 256) {
        int bi = idx >> 7, e = idx & 127;
        eL[bi * 128 + e] = edge[(size_t)(b0 + bi) * 128 + e];
    }
    __syncthreads();
    float ag[4] = {0, 0, 0, 0}, asr[4] = {0, 0, 0, 0}, ah[4] = {0, 0, 0, 0};
    for (int e = 0; e < 128; e++) {
        float wg = Wgate[e * 256 + t];
        float wsc = Wscale[e * 256 + t];
        float wsh = Wshift[e * 256 + t];
        #pragma unroll
        for (int bi = 0; bi < 4; bi++) {
            float xv = eL[bi * 128 + e];
            ag[bi] = fmaf(xv, wg, ag[bi]);
            asr[bi] = fmaf(xv, wsc, asr[bi]);
            ah[bi] = fmaf(xv, wsh, ah[bi]);
        }
    }
    float bg = bgate[t], bs = bscale[t], bsh = bshift[t];
    #pragma unroll
    for (int bi = 0; bi < 4; bi++) {
        float g = 1.0f / (1.0f + __expf(-(ag[bi] + bg)));
        float sc = tanhf(asr[bi] + bs);
        float sh = ah[bi] + bsh;
        sp[(size_t)(b0 + bi) * 256 + t] = (1.0f + sc) * g;
        tp[(size_t)(b0 + bi) * 256 + t] = sh * g;
    }
    if (t < 64) {
        int bi = t >> 4, o = t & 15, h = o & 7;
        const float* W = (o < 8) ? Wbias : Whead;
        float a = 0.0f;
        for (int e = 0; e < 128; e++) a = fmaf(eL[bi * 128 + e], W[e * 8 + h], a);
        float val = (o < 8) ? (a + bbias[h]) : tanhf(a + bhead[h]);
        ebhs[(size_t)(b0 + bi) * 16 + o] = val;
    }
}

// ---------------------------------------------------------------------------
// K2: Q = x_q @ Wq + bq, then U[j][(b,q,h)] = sum_{d in head} Wk[j,d] Q[(q),d]
// 256 blocks x 4 batches (8 q-rows, mirrored to 16 for full MFMA tiles).
// ---------------------------------------------------------------------------
__global__ __launch_bounds__(256) void k_qu(
    const float* __restrict__ node, const uint16_t* __restrict__ WqT,
    const uint16_t* __restrict__ WkB, const float* __restrict__ bq,
    uint16_t* __restrict__ U)
{
    __shared__ uint16_t xq[16 * 264];
    __shared__ uint16_t QL[16 * 264];
    const int t = threadIdx.x, lane = t & 63, w = t >> 6, c = lane & 15, quad = lane >> 4;
    const int b0 = blockIdx.x * 4;
    // stage x_q rows (rows 8..15 mirror 0..7)
    #pragma unroll
    for (int i = 0; i < 4; i++) {
        int flat4 = i * 256 + t;
        int row = flat4 >> 6, c4 = flat4 & 63;
        int r = row & 7;
        int bb = b0 + (r >> 1);
        int s = (r & 1) ? 127 : 63;
        const float4 v = *(const float4*)(node + ((size_t)(bb * 128 + s)) * 256 + c4 * 4);
        uint2 pv; pv.x = pack2(v.x, v.y); pv.y = pack2(v.z, v.w);
        *(uint2*)&xq[row * 264 + c4 * 4] = pv;
    }
    __syncthreads();
    // GEMM1: Q(16x256) = xq @ Wq; wave w handles col tiles nt = 4w..4w+3
    f32x4 zero = {0, 0, 0, 0};
    f32x4 acc[4];
    #pragma unroll
    for (int i = 0; i < 4; i++) acc[i] = zero;
    #pragma unroll
    for (int kk = 0; kk < 8; kk++) {
        bf16x8 afr = *(const bf16x8*)&xq[c * 264 + kk * 32 + quad * 8];
        #pragma unroll
        for (int i = 0; i < 4; i++) {
            int nt = w * 4 + i;
            bf16x8 bfr = *(const bf16x8*)&WqT[(size_t)(nt * 16 + c) * 264 + kk * 32 + quad * 8];
            acc[i] = MFMA16(afr, bfr, acc[i]);
        }
    }
    // write Q rows to QL (rows 8..15 are automatic mirrors)
    #pragma unroll
    for (int i = 0; i < 4; i++) {
        int nt = w * 4 + i;
        float bqv = bq[nt * 16 + c];
        #pragma unroll
        for (int r = 0; r < 4; r++) {
            QL[(quad * 4 + r) * 264 + nt * 16 + c] = f2bf(acc[i][r] + bqv);
        }
    }
    __syncthreads();
    // GEMM2: per head h, U tile = Wk(j x 32) @ Q^T(32 x 8)
    for (int hh = 0; hh < 8; hh++) {
        bf16x8 bfr = *(const bf16x8*)&QL[c * 264 + hh * 32 + quad * 8];
        #pragma unroll
        for (int i = 0; i < 4; i++) {
            int mt = w * 4 + i;
            bf16x8 afr = *(const bf16x8*)&WkB[(size_t)(mt * 16 + c) * 264 + hh * 32 + quad * 8];
            f32x4 d = MFMA16(afr, bfr, zero);
            if (c < 8) {
                int bb = b0 + (c >> 1);
                int qh = (c & 1) * 8 + hh;
                uint2 pk; pk.x = pack2(d[0], d[1]); pk.y = pack2(d[2], d[3]);
                *(uint2*)&U[((size_t)(bb * 16 + qh)) * 256 + mt * 16 + quad * 4] = pk;
            }
        }
    }
}

// ---------------------------------------------------------------------------
// K3 (hot): per batch: stream x once; S = x@U; online softmax (2 chunks of 64
// keys); Y = p@x accumulated in regs with alpha-rescale; write Y bf16
// (head-major layout: Y[(h*2048 + b*2 + q)][256]).
// ---------------------------------------------------------------------------
__global__ __launch_bounds__(256, 2) void k_main(
    const float* __restrict__ node,
    const uint16_t* __restrict__ U,
    const float* __restrict__ ebhs,
    uint16_t* __restrict__ Y)
{
    __shared__ uint16_t xc[64 * 264];   // x chunk bf16 (padded stride)
    __shared__ uint16_t uL[16 * 264];   // U^T rows [(q,h)][kd]
    __shared__ uint16_t pL[16 * 72];    // unnormalized p chunk [(q,h)][64]
    __shared__ float wred[2][16][4];
    __shared__ float stM[16], stL[16], stA[16];
    __shared__ float ebhsL[16];
    const int b = blockIdx.x;
    const int t = threadIdx.x, lane = t & 63, w = t >> 6, c = lane & 15, quad = lane >> 4;
    #pragma unroll
    for (int i = 0; i < 2; i++) {
        int flat = i * 256 + t;
        int row = flat >> 5, c16 = flat & 31;
        uint4 v = *(const uint4*)&U[((size_t)b * 16 + row) * 256 + c16 * 8];
        *(uint4*)&uL[row * 264 + c16 * 8] = v;
    }
    if (t < 16) { ebhsL[t] = ebhs[(size_t)b * 16 + t]; stM[t] = -1e30f; stL[t] = 0.0f; }
    __syncthreads();
    const int q = c >> 3, h = c & 7;
    const float scaleF = 0.17677669529663687f * (1.0f + ebhsL[8 + h]); // 1/sqrt(32)*(1+hs)
    const float ebv = ebhsL[h];
    f32x4 zero = {0, 0, 0, 0};
    f32x4 yacc[4];
    #pragma unroll
    for (int tt = 0; tt < 4; tt++) yacc[tt] = zero;

    for (int ch = 0; ch < 2; ch++) {
        // stage x chunk (64 rows x 256 fp32 -> bf16)
        #pragma unroll
        for (int i = 0; i < 16; i++) {
            int flat4 = i * 256 + t;
            int row = flat4 >> 6, c4 = flat4 & 63;
            const float4 v = *(const float4*)(node + ((size_t)b * 128 + ch * 64 + row) * 256 + c4 * 4);
            uint2 pv; pv.x = pack2(v.x, v.y); pv.y = pack2(v.z, v.w);
            *(uint2*)&xc[row * 264 + c4 * 4] = pv;
        }
        __syncthreads();
        // S chunk: wave w -> key rows [16w,16w+16)
        f32x4 sacc = zero;
        #pragma unroll
        for (int kk = 0; kk < 8; kk++) {
            bf16x8 afr = *(const bf16x8*)&xc[(w * 16 + c) * 264 + kk * 32 + quad * 8];
            bf16x8 bfr = *(const bf16x8*)&uL[c * 264 + kk * 32 + quad * 8];
            sacc = MFMA16(afr, bfr, sacc);
        }
        float v0[4];
        #pragma unroll
        for (int r = 0; r < 4; r++) {
            int krow = ch * 64 + w * 16 + quad * 4 + r;
            float x = sacc[r] * scaleF;
            if ((q == 0 && krow == 127) || (q == 1 && krow == 63)) x += ebv;
            v0[r] = x;
        }
        // online softmax bookkeeping
        float lmax = fmaxf(fmaxf(v0[0], v0[1]), fmaxf(v0[2], v0[3]));
        lmax = fmaxf(lmax, __shfl_xor(lmax, 16, 64));
        lmax = fmaxf(lmax, __shfl_xor(lmax, 32, 64));
        if (lane < 16) wred[0][c][w] = lmax;
        __syncthreads();
        float cmax = fmaxf(fmaxf(wred[0][c][0], wred[0][c][1]), fmaxf(wred[0][c][2], wred[0][c][3]));
        float mold = stM[c];
        float mnew = fmaxf(mold, cmax);
        float alpha = __expf(mold - mnew);
        float p0[4]; float lsum = 0.0f;
        #pragma unroll
        for (int r = 0; r < 4; r++) { p0[r] = __expf(v0[r] - mnew); lsum += p0[r]; }
        lsum += __shfl_xor(lsum, 16, 64);
        lsum += __shfl_xor(lsum, 32, 64);
        if (lane < 16) wred[1][c][w] = lsum;
        __syncthreads();
        if (w == 0 && lane < 16) {
            float csum = wred[1][c][0] + wred[1][c][1] + wred[1][c][2] + wred[1][c][3];
            stL[c] = stL[c] * alpha + csum;
            stM[c] = mnew;
            stA[c] = alpha;
        }
        {
            uint2 pk; pk.x = pack2(p0[0], p0[1]); pk.y = pack2(p0[2], p0[3]);
            *(uint2*)&pL[c * 72 + w * 16 + quad * 4] = pk;
        }
        __syncthreads();
        // Y chunk: rescale acc by alpha(row qh), then p @ x_chunk
        float av[4];
        #pragma unroll
        for (int r = 0; r < 4; r++) av[r] = stA[quad * 4 + r];
        #pragma unroll
        for (int tt = 0; tt < 4; tt++)
            #pragma unroll
            for (int r = 0; r < 4; r++) yacc[tt][r] *= av[r];
        #pragma unroll
        for (int kk = 0; kk < 2; kk++) {
            bf16x8 afr = *(const bf16x8*)&pL[c * 72 + kk * 32 + quad * 8];
            int kbase = kk * 32 + quad * 8;
            #pragma unroll
            for (int tt = 0; tt < 4; tt++) {
                int n = w * 64 + tt * 16 + c;
                union { bf16x8 v; uint32_t u[4]; } bb;
                #pragma unroll
                for (int jj = 0; jj < 4; jj++) {
                    uint32_t lo = xc[(kbase + 2 * jj) * 264 + n];
                    uint32_t hi = xc[(kbase + 2 * jj + 1) * 264 + n];
                    bb.u[jj] = lo | (hi << 16);
                }
                yacc[tt] = MFMA16(afr, bb.v, yacc[tt]);
            }
        }
        __syncthreads();
    }
    float invl[4];
    #pragma unroll
    for (int r = 0; r < 4; r++) invl[r] = 1.0f / stL[quad * 4 + r];
    #pragma unroll
    for (int tt = 0; tt < 4; tt++) {
        int n = w * 64 + tt * 16 + c;
        #pragma unroll
        for (int r = 0; r < 4; r++) {
            int qh = quad * 4 + r;
            int hq = qh & 7, qq = qh >> 3;
            Y[((size_t)(hq * 2048 + b * 2 + qq)) * 256 + n] = f2bf(yacc[tt][r] * invl[r]);
        }
    }
}

// ---------------------------------------------------------------------------
// K4: out = ((Y_h @ Wv_h + bv) * s' + t') @ Wo + bo.  128 blocks x 16 rows.
// Stages 2 heads per iteration so all 4 waves work.
// ---------------------------------------------------------------------------
__global__ __launch_bounds__(256) void k_out(
    const uint16_t* __restrict__ Y,
    const uint16_t* __restrict__ WvT, const uint16_t* __restrict__ WoT,
    const float* __restrict__ bv, const float* __restrict__ bo,
    const float* __restrict__ sp, const float* __restrict__ tp,
    float* __restrict__ out)
{
    __shared__ uint16_t yh[2 * 16 * 264];
    __shared__ uint16_t zm[16 * 264];
    const int t = threadIdx.x, lane = t & 63, w = t >> 6, c = lane & 15, quad = lane >> 4;
    const int R0 = blockIdx.x * 16;
    f32x4 zero = {0, 0, 0, 0};
    for (int hp = 0; hp < 4; hp++) {
        __syncthreads();
        #pragma unroll
        for (int i = 0; i < 4; i++) {
            int flat = i * 256 + t;
            int hl = flat >> 9, rem = flat & 511;
            int row = rem >> 5, c16 = rem & 31;
            uint4 v = *(const uint4*)&Y[((size_t)((2 * hp + hl) * 2048 + R0 + row)) * 256 + c16 * 8];
            *(uint4*)&yh[(hl * 16 + row) * 264 + c16 * 8] = v;
        }
        __syncthreads();
        int hl = w >> 1, nt = w & 1;
        int h = 2 * hp + hl;
        f32x4 zacc = zero;
        #pragma unroll
        for (int kk = 0; kk < 8; kk++) {
            bf16x8 afr = *(const bf16x8*)&yh[(hl * 16 + c) * 264 + kk * 32 + quad * 8];
            bf16x8 bfr = *(const bf16x8*)&WvT[(size_t)(h * 32 + nt * 16 + c) * 264 + kk * 32 + quad * 8];
            zacc = MFMA16(afr, bfr, zacc);
        }
        int col = h * 32 + nt * 16 + c;
        float bvv = bv[col];
        #pragma unroll
        for (int r = 0; r < 4; r++) {
            int row = quad * 4 + r;
            int b = (R0 + row) >> 1;
            float z = zacc[r] + bvv;
            zm[row * 264 + col] = f2bf(z * sp[(size_t)b * 256 + col] + tp[(size_t)b * 256 + col]);
        }
    }
    __syncthreads();
    // final: (16x256) @ Wo(256x256) + bo -> fp32 out
    #pragma unroll
    for (int i = 0; i < 4; i++) {
        int nt = w * 4 + i;
        int n = nt * 16 + c;
        f32x4 fa = zero;
        #pragma unroll
        for (int kk = 0; kk < 8; kk++) {
            bf16x8 afr = *(const bf16x8*)&zm[c * 264 + kk * 32 + quad * 8];
            bf16x8 bfr = *(const bf16x8*)&WoT[(size_t)n * 264 + kk * 32 + quad * 8];
            fa = MFMA16(afr, bfr, fa);
        }
        float bov = bo[n];
        #pragma unroll
        for (int r = 0; r < 4; r++) {
            out[(size_t)(R0 + quad * 4 + r) * 256 + n] = fa[r] + bov;
        }
    }
}

// ---------------------------------------------------------------------------
extern "C" void kernel_launch(void* const* d_in, const int* in_sizes, int n_in,
                              void* d_out, int out_size, void* d_ws, size_t ws_size,
                              hipStream_t stream) {
    const float* node   = (const float*)d_in[0];
    const float* edge   = (const float*)d_in[1];
    const float* Wq     = (const float*)d_in[2];
    const float* bq     = (const float*)d_in[3];
    const float* Wk     = (const float*)d_in[4];
    // d_in[5] = bk : provably unused (softmax-shift invariant)
    const float* Wv     = (const float*)d_in[6];
    const float* bv     = (const float*)d_in[7];
    const float* Wo     = (const float*)d_in[8];
    const float* bo     = (const float*)d_in[9];
    const float* Wbias  = (const float*)d_in[10];
    const float* bbias  = (const float*)d_in[11];
    const float* Wgate  = (const float*)d_in[12];
    const float* bgate  = (const float*)d_in[13];
    const float* Wscale = (const float*)d_in[14];
    const float* bscale = (const float*)d_in[15];
    const float* Wshift = (const float*)d_in[16];
    const float* bshift = (const float*)d_in[17];
    const float* Whead  = (const float*)d_in[18];
    const float* bhead  = (const float*)d_in[19];

    char* ws = (char*)d_ws;
    uint16_t* WqT  = (uint16_t*)(ws + 0);          // 256*264*2 = 135168
    uint16_t* WvT  = (uint16_t*)(ws + 135168);
    uint16_t* WoT  = (uint16_t*)(ws + 270336);
    uint16_t* WkB  = (uint16_t*)(ws + 405504);
    float*    spw  = (float*)(ws + 540672);        // 1 MB
    float*    tpw  = (float*)(ws + 1589248);       // 1 MB
    float*    ebhs = (float*)(ws + 2637824);       // 64 KB
    uint16_t* Uw   = (uint16_t*)(ws + 2703360);    // 8 MB
    uint16_t* Yw   = (uint16_t*)(ws + 11091968);   // 8 MB (end ~19.5 MB)

    k_wt<<<dim3(4, 4, 4), 256, 0, stream>>>(Wq, Wv, Wo, Wk, WqT, WvT, WoT, WkB);
    k_edge<<<256, 256, 0, stream>>>(edge, Wgate, bgate, Wscale, bscale, Wshift, bshift,
                                    Wbias, bbias, Whead, bhead, spw, tpw, ebhs);
    k_qu<<<256, 256, 0, stream>>>(node, WqT, WkB, bq, Uw);
    k_main<<<1024, 256, 0, stream>>>(node, Uw, ebhs, Yw);
    k_out<<<128, 256, 0, stream>>>(Yw, WvT, WoT, bv, bo, spw, tpw, (float*)d_out);
}

// Round 3
// 286.670 us; speedup vs baseline: 1.2661x; 1.0113x over previous
//
#include <hip/hip_runtime.h>
#include <cstdint>
#include <cstddef>

// Shapes (fixed): B=1024, N=2, HIST=64, D=256, E=128, NH=8, HD=32, s=128
// queries kept: s=63 (q=0), s=127 (q=1)

typedef short bf16x8 __attribute__((ext_vector_type(8)));
typedef float f32x4 __attribute__((ext_vector_type(4)));

#define MFMA16(A, B, C) __builtin_amdgcn_mfma_f32_16x16x32_bf16((A), (B), (C), 0, 0, 0)

static __device__ __forceinline__ uint16_t f2bf(float f) {
    uint32_t u = __builtin_bit_cast(uint32_t, f);
    u += 0x7FFFu + ((u >> 16) & 1u);
    return (uint16_t)(u >> 16);
}
static __device__ __forceinline__ uint32_t pack2(float a, float b) {
    return (uint32_t)f2bf(a) | ((uint32_t)f2bf(b) << 16);
}

// ---------------------------------------------------------------------------
// K0 (merged): blocks [0,64): weight transposes/converts; blocks [64,320):
// edge modulations (4 batches each).
// ---------------------------------------------------------------------------
__global__ __launch_bounds__(256) void k_prep(
    const float* __restrict__ Wq, const float* __restrict__ Wv,
    const float* __restrict__ Wo, const float* __restrict__ Wk,
    uint16_t* __restrict__ WqT, uint16_t* __restrict__ WvT,
    uint16_t* __restrict__ WoT, uint16_t* __restrict__ WkB,
    const float* __restrict__ edge,
    const float* __restrict__ Wgate, const float* __restrict__ bgate,
    const float* __restrict__ Wscale, const float* __restrict__ bscale,
    const float* __restrict__ Wshift, const float* __restrict__ bshift,
    const float* __restrict__ Wbias, const float* __restrict__ bbias,
    const float* __restrict__ Whead, const float* __restrict__ bhead,
    float* __restrict__ sp, float* __restrict__ tp, float* __restrict__ ebhs)
{
    __shared__ float smem[64 * 65];
    const int t = threadIdx.x;
    const int bid = blockIdx.x;
    if (bid < 64) {
        const int z = bid >> 4, tr = (bid >> 2) & 3, tc = bid & 3;
        if (z == 3) {
            #pragma unroll
            for (int i = 0; i < 16; i++) {
                int flat = i * 256 + t;
                int lr = flat >> 6, lc = flat & 63;
                WkB[(size_t)(tr * 64 + lr) * 264 + tc * 64 + lc] =
                    f2bf(Wk[(size_t)(tr * 64 + lr) * 256 + tc * 64 + lc]);
            }
            return;
        }
        const float* W = (z == 0) ? Wq : ((z == 1) ? Wv : Wo);
        uint16_t* O = (z == 0) ? WqT : ((z == 1) ? WvT : WoT);
        float (*tile)[65] = (float (*)[65])smem;
        #pragma unroll
        for (int i = 0; i < 16; i++) {
            int flat = i * 256 + t;
            int lr = flat >> 6, lc = flat & 63;
            tile[lr][lc] = W[(size_t)(tr * 64 + lr) * 256 + tc * 64 + lc];
        }
        __syncthreads();
        #pragma unroll
        for (int i = 0; i < 16; i++) {
            int flat = i * 256 + t;
            int orow = flat >> 6, oc = flat & 63;
            O[(size_t)(tc * 64 + orow) * 264 + tr * 64 + oc] = f2bf(tile[oc][orow]);
        }
        return;
    }
    // ---- edge path ----
    float* eL = smem; // [4][128]
    const int b0 = (bid - 64) * 4;
    for (int idx = t; idx < 512; idx += 256) {
        int bi = idx >> 7, e = idx & 127;
        eL[bi * 128 + e] = edge[(size_t)(b0 + bi) * 128 + e];
    }
    __syncthreads();
    float ag[4] = {0, 0, 0, 0}, asr[4] = {0, 0, 0, 0}, ah[4] = {0, 0, 0, 0};
    for (int e = 0; e < 128; e++) {
        float wg = Wgate[e * 256 + t];
        float wsc = Wscale[e * 256 + t];
        float wsh = Wshift[e * 256 + t];
        #pragma unroll
        for (int bi = 0; bi < 4; bi++) {
            float xv = eL[bi * 128 + e];
            ag[bi] = fmaf(xv, wg, ag[bi]);
            asr[bi] = fmaf(xv, wsc, asr[bi]);
            ah[bi] = fmaf(xv, wsh, ah[bi]);
        }
    }
    float bg = bgate[t], bs = bscale[t], bsh = bshift[t];
    #pragma unroll
    for (int bi = 0; bi < 4; bi++) {
        float g = 1.0f / (1.0f + __expf(-(ag[bi] + bg)));
        float sc = tanhf(asr[bi] + bs);
        float sh = ah[bi] + bsh;
        sp[(size_t)(b0 + bi) * 256 + t] = (1.0f + sc) * g;
        tp[(size_t)(b0 + bi) * 256 + t] = sh * g;
    }
    if (t < 64) {
        int bi = t >> 4, o = t & 15, h = o & 7;
        const float* W = (o < 8) ? Wbias : Whead;
        float a = 0.0f;
        for (int e = 0; e < 128; e++) a = fmaf(eL[bi * 128 + e], W[e * 8 + h], a);
        float val = (o < 8) ? (a + bbias[h]) : tanhf(a + bhead[h]);
        ebhs[(size_t)(b0 + bi) * 16 + o] = val;
    }
}

// ---------------------------------------------------------------------------
// K1: Q = x_q @ Wq + bq, then U[j][(b,q,h)] = sum_{d in head} Wk[j,d] Q[(q),d]
// 256 blocks x 4 batches (8 q-rows, mirrored to 16 for full MFMA tiles).
// ---------------------------------------------------------------------------
__global__ __launch_bounds__(256) void k_qu(
    const float* __restrict__ node, const uint16_t* __restrict__ WqT,
    const uint16_t* __restrict__ WkB, const float* __restrict__ bq,
    uint16_t* __restrict__ U)
{
    __shared__ uint16_t xq[16 * 264];
    __shared__ uint16_t QL[16 * 264];
    const int t = threadIdx.x, lane = t & 63, w = t >> 6, c = lane & 15, quad = lane >> 4;
    const int b0 = blockIdx.x * 4;
    #pragma unroll
    for (int i = 0; i < 4; i++) {
        int flat4 = i * 256 + t;
        int row = flat4 >> 6, c4 = flat4 & 63;
        int r = row & 7;
        int bb = b0 + (r >> 1);
        int s = (r & 1) ? 127 : 63;
        const float4 v = *(const float4*)(node + ((size_t)(bb * 128 + s)) * 256 + c4 * 4);
        uint2 pv; pv.x = pack2(v.x, v.y); pv.y = pack2(v.z, v.w);
        *(uint2*)&xq[row * 264 + c4 * 4] = pv;
    }
    __syncthreads();
    f32x4 zero = {0, 0, 0, 0};
    f32x4 acc[4];
    #pragma unroll
    for (int i = 0; i < 4; i++) acc[i] = zero;
    #pragma unroll
    for (int kk = 0; kk < 8; kk++) {
        bf16x8 afr = *(const bf16x8*)&xq[c * 264 + kk * 32 + quad * 8];
        #pragma unroll
        for (int i = 0; i < 4; i++) {
            int nt = w * 4 + i;
            bf16x8 bfr = *(const bf16x8*)&WqT[(size_t)(nt * 16 + c) * 264 + kk * 32 + quad * 8];
            acc[i] = MFMA16(afr, bfr, acc[i]);
        }
    }
    #pragma unroll
    for (int i = 0; i < 4; i++) {
        int nt = w * 4 + i;
        float bqv = bq[nt * 16 + c];
        #pragma unroll
        for (int r = 0; r < 4; r++) {
            QL[(quad * 4 + r) * 264 + nt * 16 + c] = f2bf(acc[i][r] + bqv);
        }
    }
    __syncthreads();
    for (int hh = 0; hh < 8; hh++) {
        bf16x8 bfr = *(const bf16x8*)&QL[c * 264 + hh * 32 + quad * 8];
        #pragma unroll
        for (int i = 0; i < 4; i++) {
            int mt = w * 4 + i;
            bf16x8 afr = *(const bf16x8*)&WkB[(size_t)(mt * 16 + c) * 264 + hh * 32 + quad * 8];
            f32x4 d = MFMA16(afr, bfr, zero);
            if (c < 8) {
                int bb = b0 + (c >> 1);
                int qh = (c & 1) * 8 + hh;
                uint2 pk; pk.x = pack2(d[0], d[1]); pk.y = pack2(d[2], d[3]);
                *(uint2*)&U[((size_t)(bb * 16 + qh)) * 256 + mt * 16 + quad * 4] = pk;
            }
        }
    }
}

// ---------------------------------------------------------------------------
// K2 (hot): per batch: stream x once; S = x@U; online softmax (2 chunks of 64
// keys); Y = p@x accumulated in regs with alpha-rescale; write Y bf16
// (head-major layout Y[(h*2048 + b*2 + q)][256]).
// xc uses a per-row 16-u16 circular column shift: col=(n+16*((row>>3)&3))&255
// -> PV u16 gather is bank-conflict-free (was 8-way); A-frags stay 16B-aligned.
// ---------------------------------------------------------------------------
__global__ __launch_bounds__(256, 3) void k_main(
    const float* __restrict__ node,
    const uint16_t* __restrict__ U,
    const float* __restrict__ ebhs,
    uint16_t* __restrict__ Y)
{
    __shared__ uint16_t xc[64 * 264];
    __shared__ uint16_t uL[16 * 264];
    __shared__ uint16_t pL[16 * 72];
    __shared__ float wred[2][16][4];
    __shared__ float stM[16], stL[16], stA[16];
    __shared__ float ebhsL[16];
    const int b = blockIdx.x;
    const int t = threadIdx.x, lane = t & 63, w = t >> 6, c = lane & 15, quad = lane >> 4;
    #pragma unroll
    for (int i = 0; i < 2; i++) {
        int flat = i * 256 + t;
        int row = flat >> 5, c16 = flat & 31;
        uint4 v = *(const uint4*)&U[((size_t)b * 16 + row) * 256 + c16 * 8];
        *(uint4*)&uL[row * 264 + c16 * 8] = v;
    }
    if (t < 16) { ebhsL[t] = ebhs[(size_t)b * 16 + t]; stM[t] = -1e30f; stL[t] = 0.0f; }
    __syncthreads();
    const int q = c >> 3, h = c & 7;
    const float scaleF = 0.17677669529663687f * (1.0f + ebhsL[8 + h]);
    const float ebv = ebhsL[h];
    f32x4 zero = {0, 0, 0, 0};
    f32x4 yacc[4];
    #pragma unroll
    for (int tt = 0; tt < 4; tt++) yacc[tt] = zero;

    for (int ch = 0; ch < 2; ch++) {
        // stage x chunk (64 rows x 256 fp32 -> bf16), per-row column shift
        #pragma unroll
        for (int i = 0; i < 16; i++) {
            int flat4 = i * 256 + t;
            int row = flat4 >> 6, c4 = flat4 & 63;
            const float4 v = *(const float4*)(node + ((size_t)b * 128 + ch * 64 + row) * 256 + c4 * 4);
            uint2 pv; pv.x = pack2(v.x, v.y); pv.y = pack2(v.z, v.w);
            int col = (c4 * 4 + ((row >> 3) & 3) * 16) & 255;
            *(uint2*)&xc[row * 264 + col] = pv;
        }
        __syncthreads();
        // S chunk: wave w -> key rows [16w,16w+16)
        f32x4 sacc = zero;
        {
            int arow = w * 16 + c;
            int sh = ((arow >> 3) & 3) * 16;
            #pragma unroll
            for (int kk = 0; kk < 8; kk++) {
                int colA = (kk * 32 + quad * 8 + sh) & 255;
                bf16x8 afr = *(const bf16x8*)&xc[arow * 264 + colA];
                bf16x8 bfr = *(const bf16x8*)&uL[c * 264 + kk * 32 + quad * 8];
                sacc = MFMA16(afr, bfr, sacc);
            }
        }
        float v0[4];
        #pragma unroll
        for (int r = 0; r < 4; r++) {
            int krow = ch * 64 + w * 16 + quad * 4 + r;
            float x = sacc[r] * scaleF;
            if ((q == 0 && krow == 127) || (q == 1 && krow == 63)) x += ebv;
            v0[r] = x;
        }
        float lmax = fmaxf(fmaxf(v0[0], v0[1]), fmaxf(v0[2], v0[3]));
        lmax = fmaxf(lmax, __shfl_xor(lmax, 16, 64));
        lmax = fmaxf(lmax, __shfl_xor(lmax, 32, 64));
        if (lane < 16) wred[0][c][w] = lmax;
        __syncthreads();
        float cmax = fmaxf(fmaxf(wred[0][c][0], wred[0][c][1]), fmaxf(wred[0][c][2], wred[0][c][3]));
        float mold = stM[c];
        float mnew = fmaxf(mold, cmax);
        float alpha = __expf(mold - mnew);
        float p0[4]; float lsum = 0.0f;
        #pragma unroll
        for (int r = 0; r < 4; r++) { p0[r] = __expf(v0[r] - mnew); lsum += p0[r]; }
        lsum += __shfl_xor(lsum, 16, 64);
        lsum += __shfl_xor(lsum, 32, 64);
        if (lane < 16) wred[1][c][w] = lsum;
        __syncthreads();
        if (w == 0 && lane < 16) {
            float csum = wred[1][c][0] + wred[1][c][1] + wred[1][c][2] + wred[1][c][3];
            stL[c] = stL[c] * alpha + csum;
            stM[c] = mnew;
            stA[c] = alpha;
        }
        {
            uint2 pk; pk.x = pack2(p0[0], p0[1]); pk.y = pack2(p0[2], p0[3]);
            *(uint2*)&pL[c * 72 + w * 16 + quad * 4] = pk;
        }
        __syncthreads();
        float av[4];
        #pragma unroll
        for (int r = 0; r < 4; r++) av[r] = stA[quad * 4 + r];
        #pragma unroll
        for (int tt = 0; tt < 4; tt++)
            #pragma unroll
            for (int r = 0; r < 4; r++) yacc[tt][r] *= av[r];
        #pragma unroll
        for (int kk = 0; kk < 2; kk++) {
            bf16x8 afr = *(const bf16x8*)&pL[c * 72 + kk * 32 + quad * 8];
            int kbase = kk * 32 + quad * 8;
            int sh = ((kbase >> 3) & 3) * 16; // same for all 8 rows of this build
            #pragma unroll
            for (int tt = 0; tt < 4; tt++) {
                int n = w * 64 + tt * 16 + c;
                int col = (n + sh) & 255;
                union { bf16x8 v; uint32_t u[4]; } bb;
                #pragma unroll
                for (int jj = 0; jj < 4; jj++) {
                    uint32_t lo = xc[(kbase + 2 * jj) * 264 + col];
                    uint32_t hi = xc[(kbase + 2 * jj + 1) * 264 + col];
                    bb.u[jj] = lo | (hi << 16);
                }
                yacc[tt] = MFMA16(afr, bb.v, yacc[tt]);
            }
        }
        __syncthreads();
    }
    float invl[4];
    #pragma unroll
    for (int r = 0; r < 4; r++) invl[r] = 1.0f / stL[quad * 4 + r];
    #pragma unroll
    for (int tt = 0; tt < 4; tt++) {
        int n = w * 64 + tt * 16 + c;
        #pragma unroll
        for (int r = 0; r < 4; r++) {
            int qh = quad * 4 + r;
            int hq = qh & 7, qq = qh >> 3;
            Y[((size_t)(hq * 2048 + b * 2 + qq)) * 256 + n] = f2bf(yacc[tt][r] * invl[r]);
        }
    }
}

// ---------------------------------------------------------------------------
// K3: out = ((Y_h @ Wv_h + bv) * s' + t') @ Wo + bo.  128 blocks x 16 rows.
// ---------------------------------------------------------------------------
__global__ __launch_bounds__(256) void k_out(
    const uint16_t* __restrict__ Y,
    const uint16_t* __restrict__ WvT, const uint16_t* __restrict__ WoT,
    const float* __restrict__ bv, const float* __restrict__ bo,
    const float* __restrict__ sp, const float* __restrict__ tp,
    float* __restrict__ out)
{
    __shared__ uint16_t yh[2 * 16 * 264];
    __shared__ uint16_t zm[16 * 264];
    const int t = threadIdx.x, lane = t & 63, w = t >> 6, c = lane & 15, quad = lane >> 4;
    const int R0 = blockIdx.x * 16;
    f32x4 zero = {0, 0, 0, 0};
    for (int hp = 0; hp < 4; hp++) {
        __syncthreads();
        #pragma unroll
        for (int i = 0; i < 4; i++) {
            int flat = i * 256 + t;
            int hl = flat >> 9, rem = flat & 511;
            int row = rem >> 5, c16 = rem & 31;
            uint4 v = *(const uint4*)&Y[((size_t)((2 * hp + hl) * 2048 + R0 + row)) * 256 + c16 * 8];
            *(uint4*)&yh[(hl * 16 + row) * 264 + c16 * 8] = v;
        }
        __syncthreads();
        int hl = w >> 1, nt = w & 1;
        int h = 2 * hp + hl;
        f32x4 zacc = zero;
        #pragma unroll
        for (int kk = 0; kk < 8; kk++) {
            bf16x8 afr = *(const bf16x8*)&yh[(hl * 16 + c) * 264 + kk * 32 + quad * 8];
            bf16x8 bfr = *(const bf16x8*)&WvT[(size_t)(h * 32 + nt * 16 + c) * 264 + kk * 32 + quad * 8];
            zacc = MFMA16(afr, bfr, zacc);
        }
        int col = h * 32 + nt * 16 + c;
        float bvv = bv[col];
        #pragma unroll
        for (int r = 0; r < 4; r++) {
            int row = quad * 4 + r;
            int b = (R0 + row) >> 1;
            float z = zacc[r] + bvv;
            zm[row * 264 + col] = f2bf(z * sp[(size_t)b * 256 + col] + tp[(size_t)b * 256 + col]);
        }
    }
    __syncthreads();
    #pragma unroll
    for (int i = 0; i < 4; i++) {
        int nt = w * 4 + i;
        int n = nt * 16 + c;
        f32x4 fa = zero;
        #pragma unroll
        for (int kk = 0; kk < 8; kk++) {
            bf16x8 afr = *(const bf16x8*)&zm[c * 264 + kk * 32 + quad * 8];
            bf16x8 bfr = *(const bf16x8*)&WoT[(size_t)n * 264 + kk * 32 + quad * 8];
            fa = MFMA16(afr, bfr, fa);
        }
        float bov = bo[n];
        #pragma unroll
        for (int r = 0; r < 4; r++) {
            out[(size_t)(R0 + quad * 4 + r) * 256 + n] = fa[r] + bov;
        }
    }
}

// ---------------------------------------------------------------------------
extern "C" void kernel_launch(void* const* d_in, const int* in_sizes, int n_in,
                              void* d_out, int out_size, void* d_ws, size_t ws_size,
                              hipStream_t stream) {
    const float* node   = (const float*)d_in[0];
    const float* edge   = (const float*)d_in[1];
    const float* Wq     = (const float*)d_in[2];
    const float* bq     = (const float*)d_in[3];
    const float* Wk     = (const float*)d_in[4];
    // d_in[5] = bk : provably unused (softmax-shift invariant)
    const float* Wv     = (const float*)d_in[6];
    const float* bv     = (const float*)d_in[7];
    const float* Wo     = (const float*)d_in[8];
    const float* bo     = (const float*)d_in[9];
    const float* Wbias  = (const float*)d_in[10];
    const float* bbias  = (const float*)d_in[11];
    const float* Wgate  = (const float*)d_in[12];
    const float* bgate  = (const float*)d_in[13];
    const float* Wscale = (const float*)d_in[14];
    const float* bscale = (const float*)d_in[15];
    const float* Wshift = (const float*)d_in[16];
    const float* bshift = (const float*)d_in[17];
    const float* Whead  = (const float*)d_in[18];
    const float* bhead  = (const float*)d_in[19];

    char* ws = (char*)d_ws;
    uint16_t* WqT  = (uint16_t*)(ws + 0);
    uint16_t* WvT  = (uint16_t*)(ws + 135168);
    uint16_t* WoT  = (uint16_t*)(ws + 270336);
    uint16_t* WkB  = (uint16_t*)(ws + 405504);
    float*    spw  = (float*)(ws + 540672);
    float*    tpw  = (float*)(ws + 1589248);
    float*    ebhs = (float*)(ws + 2637824);
    uint16_t* Uw   = (uint16_t*)(ws + 2703360);
    uint16_t* Yw   = (uint16_t*)(ws + 11091968);

    k_prep<<<320, 256, 0, stream>>>(Wq, Wv, Wo, Wk, WqT, WvT, WoT, WkB,
                                    edge, Wgate, bgate, Wscale, bscale, Wshift, bshift,
                                    Wbias, bbias, Whead, bhead, spw, tpw, ebhs);
    k_qu<<<256, 256, 0, stream>>>(node, WqT, WkB, bq, Uw);
    k_main<<<1024, 256, 0, stream>>>(node, Uw, ebhs, Yw);
    k_out<<<128, 256, 0, stream>>>(Yw, WvT, WoT, bv, bo, spw, tpw, (float*)d_out);
}